// Round 3
// baseline (22981.367 us; speedup 1.0000x reference)
//
#include <hip/hip_runtime.h>
#include <hip/hip_bf16.h>

// Problem constants (reference: B,T,V,E,H = 16,64,32000,256,1024)
#define B_ 16
#define T_ 64
#define V_ 32000
#define E_ 256
#define H_ 1024
#define G4_ (4 * H_)      // 4096 gate width
#define KE_ (E_ + H_)     // 1280 encoder GEMM K
#define KD_ (E_ + 2*H_)   // 2304 decoder GEMM K

typedef unsigned short ushort_t;
typedef unsigned int uint_t;

// bf16 helpers for INTERNAL compressed arrays only (inputs/outputs are fp32!)
__device__ __forceinline__ float b2f(ushort_t u) {
    return __uint_as_float(((uint_t)u) << 16);
}
__device__ __forceinline__ ushort_t f2b(float f) {
    uint_t u = __float_as_uint(f);
    u = (u + 0x7fffu + ((u >> 16) & 1u)) >> 16;   // round-to-nearest-even
    return (ushort_t)u;
}
__device__ __forceinline__ float sigf(float x) {
    return 1.f / (1.f + expf(-x));
}

// ---------------------------------------------------------------------------
// Zero-init fp32 state (h ping-pong x2, c, attn, query, ctx = 6*16384 floats).
// ---------------------------------------------------------------------------
__global__ __launch_bounds__(256) void init_kernel(float* __restrict__ p, int n)
{
    int i = blockIdx.x * 256 + threadIdx.x;
    if (i < n) p[i] = 0.f;
}

// ---------------------------------------------------------------------------
// Encoder LSTM step. Grid 256 blocks x 256 threads.
// Block owns 4 hidden units (all 4 gates). Thread tid = b*16 + g*4 + u
// computes z[b][g*H + blockIdx*4 + u]. h ping-pongs between launches.
// memory is stored bf16 (internal compression).
// ---------------------------------------------------------------------------
__global__ __launch_bounds__(256) void enc_step_kernel(
    const float* __restrict__ emb, const int* __restrict__ enc_in,
    const int* __restrict__ enc_len, const float* __restrict__ Wk,
    const float* __restrict__ bias, const float* __restrict__ h_in,
    float* __restrict__ h_out, float* __restrict__ c,
    ushort_t* __restrict__ memory, int t)
{
    __shared__ __align__(16) float xs[16][128];
    __shared__ __align__(16) float zb[256];
    const int tid = threadIdx.x;
    const int u = tid & 3, g = (tid >> 2) & 3, b = tid >> 4;
    const int col = g * H_ + blockIdx.x * 4 + u;
    float a0 = bias[col], a1 = 0.f, a2 = 0.f, a3 = 0.f;
    const int sr = tid >> 4, sc = (tid & 15) * 8;

    for (int ch = 0; ch < KE_ / 128; ++ch) {
        const int kb = ch * 128;
        __syncthreads();
        if (ch < 2) {  // x = embedding row (fp32)
            const int vidx = enc_in[sr * T_ + t];
            const float* ep = emb + (size_t)vidx * E_ + kb + sc;
            #pragma unroll
            for (int i = 0; i < 8; ++i) xs[sr][sc + i] = ep[i];
        } else {       // x = h (fp32 state)
            const float* hp = h_in + sr * H_ + (kb - E_) + sc;
            #pragma unroll
            for (int i = 0; i < 8; ++i) xs[sr][sc + i] = hp[i];
        }
        __syncthreads();
        const float* wp = Wk + (size_t)kb * G4_ + col;
        #pragma unroll 4
        for (int kk = 0; kk < 128; kk += 4) {
            a0 += xs[b][kk + 0] * wp[(size_t)(kk + 0) * G4_];
            a1 += xs[b][kk + 1] * wp[(size_t)(kk + 1) * G4_];
            a2 += xs[b][kk + 2] * wp[(size_t)(kk + 2) * G4_];
            a3 += xs[b][kk + 3] * wp[(size_t)(kk + 3) * G4_];
        }
    }
    zb[tid] = (a0 + a1) + (a2 + a3);
    __syncthreads();
    if (tid < 64) {
        const int b2 = tid >> 2, u2 = tid & 3;
        const int hu = blockIdx.x * 4 + u2;
        const float zi = zb[b2 * 16 + 0 * 4 + u2];
        const float zj = zb[b2 * 16 + 1 * 4 + u2];
        const float zf = zb[b2 * 16 + 2 * 4 + u2];
        const float zo = zb[b2 * 16 + 3 * 4 + u2];
        const float cold = c[b2 * H_ + hu];
        const float cn = cold * sigf(zf + 1.f) + sigf(zi) * tanhf(zj);
        const float hn = tanhf(cn) * sigf(zo);
        const bool valid = t < enc_len[b2];
        h_out[b2 * H_ + hu] = valid ? hn : h_in[b2 * H_ + hu];
        c[b2 * H_ + hu]     = valid ? cn : cold;
        memory[((size_t)b2 * T_ + t) * H_ + hu] = f2b(valid ? hn : 0.f);
    }
}

// ---------------------------------------------------------------------------
// keys = memory @ Wm (memory bf16, Wm fp32; fp32 accumulate; bf16 result).
// Grid 4096 blocks x 256 threads; block = (row, 256-col chunk).
// ---------------------------------------------------------------------------
__global__ __launch_bounds__(256) void keys_kernel(
    const ushort_t* __restrict__ memory, const float* __restrict__ Wm,
    ushort_t* __restrict__ keys)
{
    __shared__ __align__(16) float xs[H_];
    const int r = blockIdx.x >> 2;
    const int col = ((blockIdx.x & 3) << 8) + threadIdx.x;
    for (int i = threadIdx.x; i < H_; i += 256) xs[i] = b2f(memory[(size_t)r * H_ + i]);
    __syncthreads();
    float a0 = 0.f, a1 = 0.f, a2 = 0.f, a3 = 0.f;
    #pragma unroll 4
    for (int k = 0; k < H_; k += 4) {
        a0 += xs[k + 0] * Wm[(size_t)(k + 0) * H_ + col];
        a1 += xs[k + 1] * Wm[(size_t)(k + 1) * H_ + col];
        a2 += xs[k + 2] * Wm[(size_t)(k + 2) * H_ + col];
        a3 += xs[k + 3] * Wm[(size_t)(k + 3) * H_ + col];
    }
    keys[(size_t)r * H_ + col] = f2b((a0 + a1) + (a2 + a3));
}

// ---------------------------------------------------------------------------
// Decoder LSTM step (phase A). x = [emb | attn | h], K=2304.
// ---------------------------------------------------------------------------
__global__ __launch_bounds__(256) void dec_lstm_kernel(
    const float* __restrict__ emb, const int* __restrict__ dec_in,
    const float* __restrict__ Wk, const float* __restrict__ bias,
    const float* __restrict__ attn, const float* __restrict__ h_in,
    float* __restrict__ h_out, float* __restrict__ c, int t)
{
    __shared__ __align__(16) float xs[16][128];
    __shared__ __align__(16) float zb[256];
    const int tid = threadIdx.x;
    const int u = tid & 3, g = (tid >> 2) & 3, b = tid >> 4;
    const int col = g * H_ + blockIdx.x * 4 + u;
    float a0 = bias[col], a1 = 0.f, a2 = 0.f, a3 = 0.f;
    const int sr = tid >> 4, sc = (tid & 15) * 8;

    for (int ch = 0; ch < KD_ / 128; ++ch) {
        const int kb = ch * 128;
        __syncthreads();
        if (ch < 2) {          // rows 0..255: embedding (fp32)
            const int vidx = dec_in[sr * T_ + t];
            const float* ep = emb + (size_t)vidx * E_ + kb + sc;
            #pragma unroll
            for (int i = 0; i < 8; ++i) xs[sr][sc + i] = ep[i];
        } else if (ch < 10) {  // rows 256..1279: attn state (fp32)
            const float* ap = attn + sr * H_ + (kb - E_) + sc;
            #pragma unroll
            for (int i = 0; i < 8; ++i) xs[sr][sc + i] = ap[i];
        } else {               // rows 1280..2303: h (fp32)
            const float* hp = h_in + sr * H_ + (kb - E_ - H_) + sc;
            #pragma unroll
            for (int i = 0; i < 8; ++i) xs[sr][sc + i] = hp[i];
        }
        __syncthreads();
        const float* wp = Wk + (size_t)kb * G4_ + col;
        #pragma unroll 4
        for (int kk = 0; kk < 128; kk += 4) {
            a0 += xs[b][kk + 0] * wp[(size_t)(kk + 0) * G4_];
            a1 += xs[b][kk + 1] * wp[(size_t)(kk + 1) * G4_];
            a2 += xs[b][kk + 2] * wp[(size_t)(kk + 2) * G4_];
            a3 += xs[b][kk + 3] * wp[(size_t)(kk + 3) * G4_];
        }
    }
    zb[tid] = (a0 + a1) + (a2 + a3);
    __syncthreads();
    if (tid < 64) {
        const int b2 = tid >> 2, u2 = tid & 3;
        const int hu = blockIdx.x * 4 + u2;
        const float zi = zb[b2 * 16 + 0 * 4 + u2];
        const float zj = zb[b2 * 16 + 1 * 4 + u2];
        const float zf = zb[b2 * 16 + 2 * 4 + u2];
        const float zo = zb[b2 * 16 + 3 * 4 + u2];
        const float cold = c[b2 * H_ + hu];
        const float cn = cold * sigf(zf + 1.f) + sigf(zi) * tanhf(zj);
        const float hn = tanhf(cn) * sigf(zo);
        h_out[b2 * H_ + hu] = hn;   // decoder carry is unmasked
        c[b2 * H_ + hu] = cn;
    }
}

// ---------------------------------------------------------------------------
// Phase B: query = h2 @ Wq.  Grid 64 blocks x 256 threads.
// ---------------------------------------------------------------------------
__global__ __launch_bounds__(256) void query_kernel(
    const float* __restrict__ h2, const float* __restrict__ Wq,
    float* __restrict__ query)
{
    __shared__ __align__(16) float xs[16][128];
    const int tid = threadIdx.x;
    const int b = tid >> 4, cc = tid & 15;
    const int col = blockIdx.x * 16 + cc;
    float a0 = 0.f, a1 = 0.f, a2 = 0.f, a3 = 0.f;
    const int sr = tid >> 4, sc = (tid & 15) * 8;
    for (int ch = 0; ch < H_ / 128; ++ch) {
        const int kb = ch * 128;
        __syncthreads();
        const float* hp = h2 + sr * H_ + kb + sc;
        #pragma unroll
        for (int i = 0; i < 8; ++i) xs[sr][sc + i] = hp[i];
        __syncthreads();
        const float* wp = Wq + (size_t)kb * H_ + col;
        #pragma unroll 4
        for (int kk = 0; kk < 128; kk += 4) {
            a0 += xs[b][kk + 0] * wp[(size_t)(kk + 0) * H_];
            a1 += xs[b][kk + 1] * wp[(size_t)(kk + 1) * H_];
            a2 += xs[b][kk + 2] * wp[(size_t)(kk + 2) * H_];
            a3 += xs[b][kk + 3] * wp[(size_t)(kk + 3) * H_];
        }
    }
    query[b * H_ + col] = (a0 + a1) + (a2 + a3);
}

// ---------------------------------------------------------------------------
// Phase C: scores -> masked softmax -> context.  Grid 16 blocks (one per b).
// keys/memory are bf16 (internal); v_att fp32.
// ---------------------------------------------------------------------------
__global__ __launch_bounds__(256) void attn_ctx_kernel(
    const float* __restrict__ query, const ushort_t* __restrict__ keys,
    const ushort_t* __restrict__ memory, const float* __restrict__ v_att,
    const int* __restrict__ enc_len, float* __restrict__ ctx)
{
    const int b = blockIdx.x, tid = threadIdx.x;
    __shared__ __align__(16) float q[H_];
    __shared__ __align__(16) float vv[H_];
    __shared__ __align__(16) float sc[T_];
    for (int i = tid; i < H_; i += 256) { q[i] = query[b * H_ + i]; vv[i] = v_att[i]; }
    __syncthreads();
    const int w = tid >> 6, lane = tid & 63;
    for (int tt = 0; tt < 16; ++tt) {
        const int t = w * 16 + tt;
        const ushort_t* kp = keys + ((size_t)b * T_ + t) * H_;
        float p = 0.f;
        #pragma unroll 4
        for (int ii = 0; ii < 16; ++ii) {
            const int hh = lane + ii * 64;
            p += tanhf(b2f(kp[hh]) + q[hh]) * vv[hh];
        }
        for (int off = 32; off; off >>= 1) p += __shfl_xor(p, off);
        if (lane == 0) sc[t] = p;
    }
    __syncthreads();
    const int len = enc_len[b];
    if (tid < 64) {
        float s = (tid < len) ? sc[tid] : -1e9f;
        float m = s;
        for (int off = 32; off; off >>= 1) m = fmaxf(m, __shfl_xor(m, off));
        float e = expf(s - m);
        float sum = e;
        for (int off = 32; off; off >>= 1) sum += __shfl_xor(sum, off);
        sc[tid] = e / sum;
    }
    __syncthreads();
    #pragma unroll
    for (int cc = 0; cc < 4; ++cc) {
        const int col = tid + cc * 256;
        float a = 0.f;
        #pragma unroll 4
        for (int t2 = 0; t2 < T_; ++t2)
            a += sc[t2] * b2f(memory[((size_t)b * T_ + t2) * H_ + col]);
        ctx[b * H_ + col] = a;
    }
}

// ---------------------------------------------------------------------------
// Phase D: attn2 = [h2|ctx] @ attn_kernel; update attn state; write dec_out
// (bf16 internal, zeroed where finished).  Grid 64 blocks x 256 threads.
// ---------------------------------------------------------------------------
__global__ __launch_bounds__(256) void attn_out_kernel(
    const float* __restrict__ h2, const float* __restrict__ ctx,
    const float* __restrict__ attn_k, const int* __restrict__ dec_len,
    float* __restrict__ attn_state, ushort_t* __restrict__ dec_out, int t)
{
    __shared__ __align__(16) float xs[16][128];
    const int tid = threadIdx.x;
    const int b = tid >> 4, cc = tid & 15;
    const int col = blockIdx.x * 16 + cc;
    float a0 = 0.f, a1 = 0.f, a2 = 0.f, a3 = 0.f;
    const int sr = tid >> 4, sc = (tid & 15) * 8;
    for (int ch = 0; ch < (2 * H_) / 128; ++ch) {
        const int kb = ch * 128;
        __syncthreads();
        const float* src = (ch < 8) ? (h2 + sr * H_ + kb + sc)
                                    : (ctx + sr * H_ + (kb - H_) + sc);
        #pragma unroll
        for (int i = 0; i < 8; ++i) xs[sr][sc + i] = src[i];
        __syncthreads();
        const float* wp = attn_k + (size_t)kb * H_ + col;
        #pragma unroll 4
        for (int kk = 0; kk < 128; kk += 4) {
            a0 += xs[b][kk + 0] * wp[(size_t)(kk + 0) * H_];
            a1 += xs[b][kk + 1] * wp[(size_t)(kk + 1) * H_];
            a2 += xs[b][kk + 2] * wp[(size_t)(kk + 2) * H_];
            a3 += xs[b][kk + 3] * wp[(size_t)(kk + 3) * H_];
        }
    }
    const float val = (a0 + a1) + (a2 + a3);
    attn_state[b * H_ + col] = val;                    // carry (unmasked)
    const bool fin = t >= dec_len[b];
    dec_out[((size_t)b * T_ + t) * H_ + col] = f2b(fin ? 0.f : val);
}

// ---------------------------------------------------------------------------
// logits = dec_out(bf16 [1024,1024]) @ out_kernel(fp32 [1024,32000]) -> fp32.
// MFMA 16x16x32_bf16 (B converted to bf16 during staging), fp32 accumulate.
// ---------------------------------------------------------------------------
typedef __attribute__((ext_vector_type(8))) short short8;
typedef __attribute__((ext_vector_type(4))) float float4v;

__global__ __launch_bounds__(256) void logits_kernel(
    const ushort_t* __restrict__ A, const float* __restrict__ Bw,
    float* __restrict__ out)
{
    __shared__ __align__(16) ushort_t As[64][40];
    __shared__ __align__(16) ushort_t Bs[64][40];   // transposed: Bs[n][k]
    const int tid = threadIdx.x;
    const int m0 = blockIdx.x * 64;
    const int n0 = blockIdx.y * 64;
    const int wv = tid >> 6, lane = tid & 63;
    const int ml = lane & 15, quad = lane >> 4;

    float4v acc[4];
    #pragma unroll
    for (int nn = 0; nn < 4; ++nn) acc[nn] = (float4v){0.f, 0.f, 0.f, 0.f};

    for (int kb = 0; kb < 1024; kb += 32) {
        __syncthreads();
        {   // stage A: 64 rows x 32 k (bf16), vectorized 16B
            const int r = tid >> 2, c0 = (tid & 3) * 8;
            const uint4 v = *(const uint4*)(A + (size_t)(m0 + r) * 1024 + kb + c0);
            *(uint4*)&As[r][c0] = v;
        }
        {   // stage B transposed + fp32->bf16: coalesced global reads
            const int cB = tid & 63, kq = tid >> 6;
            #pragma unroll
            for (int i = 0; i < 8; ++i) {
                const int k = kq * 8 + i;
                Bs[cB][k] = f2b(Bw[(size_t)(kb + k) * V_ + n0 + cB]);
            }
        }
        __syncthreads();
        const short8 af = *(const short8*)&As[wv * 16 + ml][quad * 8];
        #pragma unroll
        for (int nn = 0; nn < 4; ++nn) {
            const short8 bfg = *(const short8*)&Bs[nn * 16 + ml][quad * 8];
            acc[nn] = __builtin_amdgcn_mfma_f32_16x16x32_bf16(af, bfg, acc[nn], 0, 0, 0);
        }
    }
    #pragma unroll
    for (int nn = 0; nn < 4; ++nn) {
        #pragma unroll
        for (int rg = 0; rg < 4; ++rg) {
            const int row = m0 + wv * 16 + quad * 4 + rg;
            const int colo = n0 + nn * 16 + ml;
            out[(size_t)row * V_ + colo] = acc[nn][rg];
        }
    }
}

// ---------------------------------------------------------------------------
extern "C" void kernel_launch(void* const* d_in, const int* in_sizes, int n_in,
                              void* d_out, int out_size, void* d_ws, size_t ws_size,
                              hipStream_t stream) {
    (void)in_sizes; (void)n_in; (void)out_size; (void)ws_size;
    const int*   enc_in  = (const int*)d_in[0];
    const int*   dec_in  = (const int*)d_in[1];
    const int*   enc_len = (const int*)d_in[2];
    const int*   dec_len = (const int*)d_in[3];
    const float* emb     = (const float*)d_in[4];
    const float* encK    = (const float*)d_in[5];
    const float* encB    = (const float*)d_in[6];
    const float* decK    = (const float*)d_in[7];
    const float* decB    = (const float*)d_in[8];
    const float* Wm      = (const float*)d_in[9];
    const float* Wq      = (const float*)d_in[10];
    const float* v_att   = (const float*)d_in[11];
    const float* attnK   = (const float*)d_in[12];
    const float* outK    = (const float*)d_in[13];
    float* out = (float*)d_out;

    // workspace layout: fp32 small state first, then bf16 big arrays (~6.6 MB)
    float* hbuf   = (float*)d_ws;                 // 2 x [16,1024] ping-pong
    float* cbuf   = hbuf + 2 * B_ * H_;           // [16,1024]
    float* attn   = cbuf + B_ * H_;               // [16,1024]
    float* query  = attn + B_ * H_;               // [16,1024]
    float* ctx    = query + B_ * H_;              // [16,1024]
    ushort_t* memory  = (ushort_t*)(ctx + B_ * H_);          // bf16 [16,64,1024]
    ushort_t* keys    = memory + (size_t)B_ * T_ * H_;       // bf16 [16,64,1024]
    ushort_t* dec_out = keys + (size_t)B_ * T_ * H_;         // bf16 [1024,1024]

    // zero fp32 state (ws is poisoned 0xAA each call): 6*16384 floats
    const int ninit = 6 * B_ * H_;
    init_kernel<<<(ninit + 255) / 256, 256, 0, stream>>>((float*)d_ws, ninit);

    for (int t = 0; t < T_; ++t) {
        float* h_in  = hbuf + (t & 1) * B_ * H_;
        float* h_out = hbuf + ((t + 1) & 1) * B_ * H_;
        enc_step_kernel<<<256, 256, 0, stream>>>(emb, enc_in, enc_len, encK, encB,
                                                 h_in, h_out, cbuf, memory, t);
    }
    keys_kernel<<<4096, 256, 0, stream>>>(memory, Wm, keys);

    for (int t = 0; t < T_; ++t) {
        float* h_in  = hbuf + (t & 1) * B_ * H_;
        float* h_out = hbuf + ((t + 1) & 1) * B_ * H_;
        dec_lstm_kernel<<<256, 256, 0, stream>>>(emb, dec_in, decK, decB, attn,
                                                 h_in, h_out, cbuf, t);
        query_kernel<<<64, 256, 0, stream>>>(h_out, Wq, query);
        attn_ctx_kernel<<<16, 256, 0, stream>>>(query, keys, memory, v_att, enc_len, ctx);
        attn_out_kernel<<<64, 256, 0, stream>>>(h_out, ctx, attnK, dec_len, attn, dec_out, t);
    }

    logits_kernel<<<dim3(16, 500), 256, 0, stream>>>(dec_out, outK, out);
}

// Round 4
// 10588.927 us; speedup vs baseline: 2.1703x; 2.1703x over previous
//
#include <hip/hip_runtime.h>
#include <hip/hip_bf16.h>

// Problem constants (reference: B,T,V,E,H = 16,64,32000,256,1024)
#define B_ 16
#define T_ 64
#define V_ 32000
#define E_ 256
#define H_ 1024
#define G4_ (4 * H_)      // 4096 gate width
#define KE_ (E_ + H_)     // 1280 encoder GEMM K
#define KD_ (E_ + 2*H_)   // 2304 decoder GEMM K
#define KSE_ (KE_ / 16)   // 80  rows per k-split (encoder)
#define KSD_ (KD_ / 16)   // 144 rows per k-split (decoder)

typedef unsigned short ushort_t;
typedef unsigned int uint_t;

__device__ __forceinline__ float b2f(ushort_t u) {
    return __uint_as_float(((uint_t)u) << 16);
}
__device__ __forceinline__ ushort_t f2b(float f) {
    uint_t u = __float_as_uint(f);
    u = (u + 0x7fffu + ((u >> 16) & 1u)) >> 16;   // round-to-nearest-even
    return (ushort_t)u;
}
__device__ __forceinline__ float sigf(float x) {
    return 1.f / (1.f + expf(-x));
}

// ---------------------------------------------------------------------------
// Zero-init fp32 state: hbuf x2, c, attn = 4*16384 floats.
// ---------------------------------------------------------------------------
__global__ __launch_bounds__(256) void init_kernel(float* __restrict__ p, int n)
{
    int i = blockIdx.x * 256 + threadIdx.x;
    if (i < n) p[i] = 0.f;
}

// ---------------------------------------------------------------------------
// Encoder LSTM GEMM (split-K partials). Grid 256 = (16 colchunk, 16 ksplit).
// thread = one of 256 consecutive gate columns -> fully coalesced weight
// reads (wave = 256B contiguous). x values are wave-uniform (scalar-load
// path). 16 batch accumulators per thread.
// zpart layout: [ks][b][4096]
// ---------------------------------------------------------------------------
__global__ __launch_bounds__(256) void enc_gemm_kernel(
    const float* __restrict__ emb, const int* __restrict__ enc_in,
    const float* __restrict__ Wk, const float* __restrict__ h_in,
    float* __restrict__ zpart, int t)
{
    const int cc = blockIdx.x & 15;
    const int ks = blockIdx.x >> 4;
    const int col = cc * 256 + threadIdx.x;
    const int k0 = ks * KSE_;

    int vidx[16];
    #pragma unroll
    for (int b = 0; b < 16; ++b) vidx[b] = enc_in[b * T_ + t];

    float acc[16];
    #pragma unroll
    for (int b = 0; b < 16; ++b) acc[b] = 0.f;

    for (int kk = 0; kk < KSE_; ++kk) {
        const int k = k0 + kk;
        const float w = Wk[(size_t)k * G4_ + col];
        if (k < E_) {
            #pragma unroll
            for (int b = 0; b < 16; ++b)
                acc[b] = fmaf(emb[(size_t)vidx[b] * E_ + k], w, acc[b]);
        } else {
            const float* hp = h_in + (k - E_);
            #pragma unroll
            for (int b = 0; b < 16; ++b)
                acc[b] = fmaf(hp[b * H_], w, acc[b]);
        }
    }
    #pragma unroll
    for (int b = 0; b < 16; ++b)
        zpart[((size_t)(ks * 16 + b)) * G4_ + col] = acc[b];
}

// ---------------------------------------------------------------------------
// Encoder gates: reduce 16 k-split partials + bias, LSTM activations,
// masked state update, write memory (fp32). Grid 64 x 256 (one thread per
// (b,hu) output).
// ---------------------------------------------------------------------------
__global__ __launch_bounds__(256) void enc_gates_kernel(
    const float* __restrict__ zpart, const float* __restrict__ bias,
    const int* __restrict__ enc_len, const float* __restrict__ h_in,
    float* __restrict__ h_out, float* __restrict__ c,
    float* __restrict__ memory, int t)
{
    const int idx = blockIdx.x * 256 + threadIdx.x;   // 0..16383
    const int b = idx >> 10, hu = idx & 1023;
    float z[4];
    #pragma unroll
    for (int g = 0; g < 4; ++g) {
        float s = bias[g * H_ + hu];
        #pragma unroll
        for (int ks = 0; ks < 16; ++ks)
            s += zpart[((size_t)(ks * 16 + b)) * G4_ + g * H_ + hu];
        z[g] = s;
    }
    const float cold = c[b * H_ + hu];
    const float cn = cold * sigf(z[2] + 1.f) + sigf(z[0]) * tanhf(z[1]);
    const float hn = tanhf(cn) * sigf(z[3]);
    const bool valid = t < enc_len[b];
    h_out[b * H_ + hu] = valid ? hn : h_in[b * H_ + hu];
    c[b * H_ + hu]     = valid ? cn : cold;
    memory[((size_t)b * T_ + t) * H_ + hu] = valid ? hn : 0.f;
}

// ---------------------------------------------------------------------------
// keys = memory[1024,1024] @ Wm[1024,1024]. Grid 256 = (64 rowtile, 4 cc).
// thread = col; 16 row accumulators; Wm read once, coalesced.
// ---------------------------------------------------------------------------
__global__ __launch_bounds__(256) void keys_gemm_kernel(
    const float* __restrict__ memory, const float* __restrict__ Wm,
    float* __restrict__ keys)
{
    const int rt = blockIdx.x >> 2;
    const int cc = blockIdx.x & 3;
    const int col = cc * 256 + threadIdx.x;
    float acc[16];
    #pragma unroll
    for (int m = 0; m < 16; ++m) acc[m] = 0.f;
    for (int k = 0; k < H_; ++k) {
        const float w = Wm[(size_t)k * H_ + col];
        const float* mp = memory + (size_t)(rt * 16) * H_ + k;
        #pragma unroll
        for (int m = 0; m < 16; ++m)
            acc[m] = fmaf(mp[(size_t)m * H_], w, acc[m]);
    }
    #pragma unroll
    for (int m = 0; m < 16; ++m)
        keys[(size_t)(rt * 16 + m) * H_ + col] = acc[m];
}

// ---------------------------------------------------------------------------
// Decoder LSTM GEMM (split-K partials). x = [emb | attn | h], K=2304.
// Grid 256 = (16 colchunk, 16 ksplit).
// ---------------------------------------------------------------------------
__global__ __launch_bounds__(256) void dec_gemm_kernel(
    const float* __restrict__ emb, const int* __restrict__ dec_in,
    const float* __restrict__ Wk, const float* __restrict__ attn,
    const float* __restrict__ h_in, float* __restrict__ zpart, int t)
{
    const int cc = blockIdx.x & 15;
    const int ks = blockIdx.x >> 4;
    const int col = cc * 256 + threadIdx.x;
    const int k0 = ks * KSD_;

    int vidx[16];
    #pragma unroll
    for (int b = 0; b < 16; ++b) vidx[b] = dec_in[b * T_ + t];

    float acc[16];
    #pragma unroll
    for (int b = 0; b < 16; ++b) acc[b] = 0.f;

    for (int kk = 0; kk < KSD_; ++kk) {
        const int k = k0 + kk;
        const float w = Wk[(size_t)k * G4_ + col];
        if (k < E_) {
            #pragma unroll
            for (int b = 0; b < 16; ++b)
                acc[b] = fmaf(emb[(size_t)vidx[b] * E_ + k], w, acc[b]);
        } else if (k < E_ + H_) {
            const float* ap = attn + (k - E_);
            #pragma unroll
            for (int b = 0; b < 16; ++b)
                acc[b] = fmaf(ap[b * H_], w, acc[b]);
        } else {
            const float* hp = h_in + (k - E_ - H_);
            #pragma unroll
            for (int b = 0; b < 16; ++b)
                acc[b] = fmaf(hp[b * H_], w, acc[b]);
        }
    }
    #pragma unroll
    for (int b = 0; b < 16; ++b)
        zpart[((size_t)(ks * 16 + b)) * G4_ + col] = acc[b];
}

// ---------------------------------------------------------------------------
// Decoder gates (no masking on carry). Grid 64 x 256.
// ---------------------------------------------------------------------------
__global__ __launch_bounds__(256) void dec_gates_kernel(
    const float* __restrict__ zpart, const float* __restrict__ bias,
    float* __restrict__ h_out, float* __restrict__ c)
{
    const int idx = blockIdx.x * 256 + threadIdx.x;
    const int b = idx >> 10, hu = idx & 1023;
    float z[4];
    #pragma unroll
    for (int g = 0; g < 4; ++g) {
        float s = bias[g * H_ + hu];
        #pragma unroll
        for (int ks = 0; ks < 16; ++ks)
            s += zpart[((size_t)(ks * 16 + b)) * G4_ + g * H_ + hu];
        z[g] = s;
    }
    const float cold = c[b * H_ + hu];
    const float cn = cold * sigf(z[2] + 1.f) + sigf(z[0]) * tanhf(z[1]);
    const float hn = tanhf(cn) * sigf(z[3]);
    h_out[b * H_ + hu] = hn;
    c[b * H_ + hu] = cn;
}

// ---------------------------------------------------------------------------
// query partials: q = h2 @ Wq, split-K 8. Grid 32 = (4 cc, 8 ks).
// qpart layout: [ks][b][1024]
// ---------------------------------------------------------------------------
__global__ __launch_bounds__(256) void query_gemm_kernel(
    const float* __restrict__ h2, const float* __restrict__ Wq,
    float* __restrict__ qpart)
{
    const int cc = blockIdx.x & 3;
    const int ks = blockIdx.x >> 2;     // 0..7
    const int col = cc * 256 + threadIdx.x;
    const int k0 = ks * 128;
    float acc[16];
    #pragma unroll
    for (int b = 0; b < 16; ++b) acc[b] = 0.f;
    for (int kk = 0; kk < 128; ++kk) {
        const int k = k0 + kk;
        const float w = Wq[(size_t)k * H_ + col];
        const float* hp = h2 + k;
        #pragma unroll
        for (int b = 0; b < 16; ++b)
            acc[b] = fmaf(hp[b * H_], w, acc[b]);
    }
    #pragma unroll
    for (int b = 0; b < 16; ++b)
        qpart[((size_t)(ks * 16 + b)) * H_ + col] = acc[b];
}

// ---------------------------------------------------------------------------
// scores[b][t] = sum_h tanh(keys[b,t,h] + q[b,h]) * v[h], q reduced from
// qpart on the fly. Grid 1024 = (16 b, 64 t), 256 threads (4 h each).
// ---------------------------------------------------------------------------
__global__ __launch_bounds__(256) void attn_scores_kernel(
    const float* __restrict__ qpart, const float* __restrict__ keys,
    const float* __restrict__ v_att, float* __restrict__ scores)
{
    const int b = blockIdx.x >> 6, t = blockIdx.x & 63;
    const int tid = threadIdx.x;
    const float* kp = keys + ((size_t)b * T_ + t) * H_;
    float s = 0.f;
    #pragma unroll
    for (int i = 0; i < 4; ++i) {
        const int h = tid + i * 256;
        float q = 0.f;
        #pragma unroll
        for (int ks = 0; ks < 8; ++ks)
            q += qpart[((size_t)(ks * 16 + b)) * H_ + h];
        s += tanhf(kp[h] + q) * v_att[h];
    }
    #pragma unroll
    for (int off = 32; off; off >>= 1) s += __shfl_xor(s, off);
    __shared__ float red[4];
    if ((tid & 63) == 0) red[tid >> 6] = s;
    __syncthreads();
    if (tid == 0) scores[b * T_ + t] = (red[0] + red[1]) + (red[2] + red[3]);
}

// ---------------------------------------------------------------------------
// masked softmax + context. Grid 64 = (16 b, 4 colchunk), 256 threads.
// ctx[b][col] = sum_t align[t] * memory[b][t][col]  (coalesced over col).
// ---------------------------------------------------------------------------
__global__ __launch_bounds__(256) void softmax_ctx_kernel(
    const float* __restrict__ scores, const float* __restrict__ memory,
    const int* __restrict__ enc_len, float* __restrict__ ctx)
{
    const int b = blockIdx.x >> 2, cc = blockIdx.x & 3;
    const int tid = threadIdx.x;
    __shared__ float al[T_];
    if (tid < 64) {
        const int len = enc_len[b];
        float s = (tid < len) ? scores[b * T_ + tid] : -1e9f;
        float m = s;
        #pragma unroll
        for (int off = 32; off; off >>= 1) m = fmaxf(m, __shfl_xor(m, off));
        float e = expf(s - m);
        float sum = e;
        #pragma unroll
        for (int off = 32; off; off >>= 1) sum += __shfl_xor(sum, off);
        al[tid] = e / sum;
    }
    __syncthreads();
    const int col = cc * 256 + tid;
    const float* mp = memory + (size_t)b * T_ * H_ + col;
    float a = 0.f;
    #pragma unroll 4
    for (int t2 = 0; t2 < T_; ++t2)
        a = fmaf(al[t2], mp[(size_t)t2 * H_], a);
    ctx[b * H_ + col] = a;
}

// ---------------------------------------------------------------------------
// attn2 partials: [h2|ctx](K=2048) @ attn_kernel, split-K 16.
// Grid 64 = (4 cc, 16 ks). apart layout: [ks][b][1024]
// ---------------------------------------------------------------------------
__global__ __launch_bounds__(256) void attnout_gemm_kernel(
    const float* __restrict__ h2, const float* __restrict__ ctx,
    const float* __restrict__ attn_k, float* __restrict__ apart)
{
    const int cc = blockIdx.x & 3;
    const int ks = blockIdx.x >> 2;     // 0..15
    const int col = cc * 256 + threadIdx.x;
    const int k0 = ks * 128;
    float acc[16];
    #pragma unroll
    for (int b = 0; b < 16; ++b) acc[b] = 0.f;
    for (int kk = 0; kk < 128; ++kk) {
        const int k = k0 + kk;
        const float w = attn_k[(size_t)k * H_ + col];
        const float* xp = (k < H_) ? (h2 + k) : (ctx + (k - H_));
        #pragma unroll
        for (int b = 0; b < 16; ++b)
            acc[b] = fmaf(xp[b * H_], w, acc[b]);
    }
    #pragma unroll
    for (int b = 0; b < 16; ++b)
        apart[((size_t)(ks * 16 + b)) * H_ + col] = acc[b];
}

// ---------------------------------------------------------------------------
// attn_out finish: reduce 16 partials -> attn state (carry, unmasked) and
// dec_out (fp32, zeroed where finished). Grid 64 x 256.
// ---------------------------------------------------------------------------
__global__ __launch_bounds__(256) void attnout_finish_kernel(
    const float* __restrict__ apart, const int* __restrict__ dec_len,
    float* __restrict__ attn_state, float* __restrict__ dec_out, int t)
{
    const int idx = blockIdx.x * 256 + threadIdx.x;
    const int b = idx >> 10, col = idx & 1023;
    float s = 0.f;
    #pragma unroll
    for (int ks = 0; ks < 16; ++ks)
        s += apart[((size_t)(ks * 16 + b)) * H_ + col];
    attn_state[b * H_ + col] = s;
    const bool fin = t >= dec_len[b];
    dec_out[((size_t)b * T_ + t) * H_ + col] = fin ? 0.f : s;
}

// ---------------------------------------------------------------------------
// logits = dec_out(fp32 [1024,1024]) @ out_kernel(fp32 [1024,32000]) -> fp32.
// Split-bf16: A = ah+al, B = bh+bl; D = ah*bh + ah*bl + al*bh (al*bl ~2^-18,
// dropped). MFMA 16x16x32_bf16, 64x64 tile. Grid (16 m, 500 n).
// ---------------------------------------------------------------------------
typedef __attribute__((ext_vector_type(8))) short short8;
typedef __attribute__((ext_vector_type(4))) float float4v;

__global__ __launch_bounds__(256) void logits_kernel(
    const float* __restrict__ A, const float* __restrict__ Bw,
    float* __restrict__ out)
{
    __shared__ __align__(16) ushort_t Ah[64][40];
    __shared__ __align__(16) ushort_t Al[64][40];
    __shared__ __align__(16) ushort_t Bh[64][40];   // transposed: [n][k]
    __shared__ __align__(16) ushort_t Bl[64][40];
    const int tid = threadIdx.x;
    const int m0 = blockIdx.x * 64;
    const int n0 = blockIdx.y * 64;
    const int wv = tid >> 6, lane = tid & 63;
    const int ml = lane & 15, quad = lane >> 4;

    float4v acc[4];
    #pragma unroll
    for (int nn = 0; nn < 4; ++nn) acc[nn] = (float4v){0.f, 0.f, 0.f, 0.f};

    for (int kb = 0; kb < 1024; kb += 32) {
        __syncthreads();
        {   // stage A: 64 rows x 32 k fp32 -> hi/lo bf16
            const int r = tid >> 2, c0 = (tid & 3) * 8;
            const float* ap = A + (size_t)(m0 + r) * 1024 + kb + c0;
            #pragma unroll
            for (int i = 0; i < 8; ++i) {
                const float f = ap[i];
                const ushort_t hi = f2b(f);
                Ah[r][c0 + i] = hi;
                Al[r][c0 + i] = f2b(f - b2f(hi));
            }
        }
        {   // stage B transposed: coalesced rows, fp32 -> hi/lo bf16
            const int cB = tid & 63, kq = tid >> 6;
            #pragma unroll
            for (int i = 0; i < 8; ++i) {
                const int k = kq * 8 + i;
                const float f = Bw[(size_t)(kb + k) * V_ + n0 + cB];
                const ushort_t hi = f2b(f);
                Bh[cB][k] = hi;
                Bl[cB][k] = f2b(f - b2f(hi));
            }
        }
        __syncthreads();
        const short8 afh = *(const short8*)&Ah[wv * 16 + ml][quad * 8];
        const short8 afl = *(const short8*)&Al[wv * 16 + ml][quad * 8];
        #pragma unroll
        for (int nn = 0; nn < 4; ++nn) {
            const short8 bfh = *(const short8*)&Bh[nn * 16 + ml][quad * 8];
            const short8 bfl = *(const short8*)&Bl[nn * 16 + ml][quad * 8];
            acc[nn] = __builtin_amdgcn_mfma_f32_16x16x32_bf16(afh, bfh, acc[nn], 0, 0, 0);
            acc[nn] = __builtin_amdgcn_mfma_f32_16x16x32_bf16(afh, bfl, acc[nn], 0, 0, 0);
            acc[nn] = __builtin_amdgcn_mfma_f32_16x16x32_bf16(afl, bfh, acc[nn], 0, 0, 0);
        }
    }
    #pragma unroll
    for (int nn = 0; nn < 4; ++nn) {
        #pragma unroll
        for (int rg = 0; rg < 4; ++rg) {
            const int row = m0 + wv * 16 + quad * 4 + rg;
            const int colo = n0 + nn * 16 + ml;
            out[(size_t)row * V_ + colo] = acc[nn][rg];
        }
    }
}

// ---------------------------------------------------------------------------
extern "C" void kernel_launch(void* const* d_in, const int* in_sizes, int n_in,
                              void* d_out, int out_size, void* d_ws, size_t ws_size,
                              hipStream_t stream) {
    (void)in_sizes; (void)n_in; (void)out_size; (void)ws_size;
    const int*   enc_in  = (const int*)d_in[0];
    const int*   dec_in  = (const int*)d_in[1];
    const int*   enc_len = (const int*)d_in[2];
    const int*   dec_len = (const int*)d_in[3];
    const float* emb     = (const float*)d_in[4];
    const float* encK    = (const float*)d_in[5];
    const float* encB    = (const float*)d_in[6];
    const float* decK    = (const float*)d_in[7];
    const float* decB    = (const float*)d_in[8];
    const float* Wm      = (const float*)d_in[9];
    const float* Wq      = (const float*)d_in[10];
    const float* v_att   = (const float*)d_in[11];
    const float* attnK   = (const float*)d_in[12];
    const float* outK    = (const float*)d_in[13];
    float* out = (float*)d_out;

    // fp32 workspace layout (~18.7 MB)
    float* hbuf    = (float*)d_ws;                      // 2 x [16,1024]
    float* cbuf    = hbuf + 2 * B_ * H_;                // [16,1024]
    float* attn    = cbuf + B_ * H_;                    // [16,1024]
    float* ctx     = attn + B_ * H_;                    // [16,1024]
    float* scores  = ctx + B_ * H_;                     // [16,64]
    float* memory  = scores + B_ * T_;                  // [16,64,1024]
    float* keys    = memory + (size_t)B_ * T_ * H_;     // [16,64,1024]
    float* dec_out = keys + (size_t)B_ * T_ * H_;       // [1024,1024]
    float* zpart   = dec_out + (size_t)B_ * T_ * H_;    // [16][16][4096]
    float* qpart   = zpart + (size_t)16 * B_ * G4_;     // [8][16][1024]
    float* apart   = qpart + (size_t)8 * B_ * H_;       // [16][16][1024]

    // zero fp32 recurrent state (ws poisoned 0xAA): hbuf x2, c, attn
    const int ninit = 4 * B_ * H_;
    init_kernel<<<(ninit + 255) / 256, 256, 0, stream>>>((float*)d_ws, ninit);

    for (int t = 0; t < T_; ++t) {
        float* h_in  = hbuf + (t & 1) * B_ * H_;
        float* h_out = hbuf + ((t + 1) & 1) * B_ * H_;
        enc_gemm_kernel<<<256, 256, 0, stream>>>(emb, enc_in, encK, h_in, zpart, t);
        enc_gates_kernel<<<64, 256, 0, stream>>>(zpart, encB, enc_len, h_in,
                                                 h_out, cbuf, memory, t);
    }
    keys_gemm_kernel<<<256, 256, 0, stream>>>(memory, Wm, keys);

    for (int t = 0; t < T_; ++t) {
        float* h_in  = hbuf + (t & 1) * B_ * H_;
        float* h2    = hbuf + ((t + 1) & 1) * B_ * H_;
        dec_gemm_kernel<<<256, 256, 0, stream>>>(emb, dec_in, decK, attn, h_in, zpart, t);
        dec_gates_kernel<<<64, 256, 0, stream>>>(zpart, decB, h2, cbuf);
        query_gemm_kernel<<<32, 256, 0, stream>>>(h2, Wq, qpart);
        attn_scores_kernel<<<1024, 256, 0, stream>>>(qpart, keys, v_att, scores);
        softmax_ctx_kernel<<<64, 256, 0, stream>>>(scores, memory, enc_len, ctx);
        attnout_gemm_kernel<<<64, 256, 0, stream>>>(h2, ctx, attnK, apart);
        attnout_finish_kernel<<<64, 256, 0, stream>>>(apart, dec_len, attn, dec_out, t);
    }

    logits_kernel<<<dim3(16, 500), 256, 0, stream>>>(dec_out, outK, out);
}

// Round 5
// 6985.840 us; speedup vs baseline: 3.2897x; 1.5158x over previous
//
#include <hip/hip_runtime.h>
#include <hip/hip_bf16.h>

// Problem constants (reference: B,T,V,E,H = 16,64,32000,256,1024)
#define B_ 16
#define T_ 64
#define V_ 32000
#define E_ 256
#define H_ 1024
#define G4_ (4 * H_)      // 4096 gate width
#define KE_ (E_ + H_)     // 1280 encoder GEMM K
#define KD_ (E_ + 2*H_)   // 2304 decoder GEMM K
#define NKS_ 32           // k-splits for enc/dec GEMMs
#define KSE_ (KE_ / NKS_) // 40  rows per k-split (encoder)
#define KSD_ (KD_ / NKS_) // 72  rows per k-split (decoder)

typedef unsigned short ushort_t;
typedef unsigned int uint_t;

__device__ __forceinline__ float b2f(ushort_t u) {
    return __uint_as_float(((uint_t)u) << 16);
}
__device__ __forceinline__ ushort_t f2b(float f) {
    uint_t u = __float_as_uint(f);
    u = (u + 0x7fffu + ((u >> 16) & 1u)) >> 16;   // round-to-nearest-even
    return (ushort_t)u;
}
__device__ __forceinline__ float sigf(float x) {
    return 1.f / (1.f + expf(-x));
}

// ---------------------------------------------------------------------------
// Zero-init fp32 state: hbuf x2, c, attn = 4*16384 floats.
// ---------------------------------------------------------------------------
__global__ __launch_bounds__(256) void init_kernel(float* __restrict__ p, int n)
{
    int i = blockIdx.x * 256 + threadIdx.x;
    if (i < n) p[i] = 0.f;
}

// ---------------------------------------------------------------------------
// Encoder LSTM GEMM (split-K partials). Grid 512 = (16 colchunk, 32 ksplit).
// thread = one of 256 consecutive gate columns -> coalesced weight reads.
// 8 waves/CU for latency hiding. zpart layout: [ks][b][4096].
// ---------------------------------------------------------------------------
__global__ __launch_bounds__(256) void enc_gemm_kernel(
    const float* __restrict__ emb, const int* __restrict__ enc_in,
    const float* __restrict__ Wk, const float* __restrict__ h_in,
    float* __restrict__ zpart, int t)
{
    const int cc = blockIdx.x & 15;
    const int ks = blockIdx.x >> 4;           // 0..31
    const int col = cc * 256 + threadIdx.x;
    const int k0 = ks * KSE_;

    int vidx[16];
    #pragma unroll
    for (int b = 0; b < 16; ++b) vidx[b] = enc_in[b * T_ + t];

    float acc[16];
    #pragma unroll
    for (int b = 0; b < 16; ++b) acc[b] = 0.f;

    for (int kk = 0; kk < KSE_; ++kk) {
        const int k = k0 + kk;
        const float w = Wk[(size_t)k * G4_ + col];
        if (k < E_) {
            #pragma unroll
            for (int b = 0; b < 16; ++b)
                acc[b] = fmaf(emb[(size_t)vidx[b] * E_ + k], w, acc[b]);
        } else {
            const float* hp = h_in + (k - E_);
            #pragma unroll
            for (int b = 0; b < 16; ++b)
                acc[b] = fmaf(hp[b * H_], w, acc[b]);
        }
    }
    #pragma unroll
    for (int b = 0; b < 16; ++b)
        zpart[((size_t)(ks * 16 + b)) * G4_ + col] = acc[b];
}

// ---------------------------------------------------------------------------
// Encoder gates: reduce 32 k-split partials + bias, LSTM activations,
// masked state update, write memory (fp32). Grid 64 x 256.
// ---------------------------------------------------------------------------
__global__ __launch_bounds__(256) void enc_gates_kernel(
    const float* __restrict__ zpart, const float* __restrict__ bias,
    const int* __restrict__ enc_len, const float* __restrict__ h_in,
    float* __restrict__ h_out, float* __restrict__ c,
    float* __restrict__ memory, int t)
{
    const int idx = blockIdx.x * 256 + threadIdx.x;   // 0..16383
    const int b = idx >> 10, hu = idx & 1023;
    float z[4];
    #pragma unroll
    for (int g = 0; g < 4; ++g) {
        float s0 = bias[g * H_ + hu], s1 = 0.f, s2 = 0.f, s3 = 0.f;
        #pragma unroll
        for (int ks = 0; ks < NKS_; ks += 4) {
            s0 += zpart[((size_t)((ks + 0) * 16 + b)) * G4_ + g * H_ + hu];
            s1 += zpart[((size_t)((ks + 1) * 16 + b)) * G4_ + g * H_ + hu];
            s2 += zpart[((size_t)((ks + 2) * 16 + b)) * G4_ + g * H_ + hu];
            s3 += zpart[((size_t)((ks + 3) * 16 + b)) * G4_ + g * H_ + hu];
        }
        z[g] = (s0 + s1) + (s2 + s3);
    }
    const float cold = c[b * H_ + hu];
    const float cn = cold * sigf(z[2] + 1.f) + sigf(z[0]) * tanhf(z[1]);
    const float hn = tanhf(cn) * sigf(z[3]);
    const bool valid = t < enc_len[b];
    h_out[b * H_ + hu] = valid ? hn : h_in[b * H_ + hu];
    c[b * H_ + hu]     = valid ? cn : cold;
    memory[((size_t)b * T_ + t) * H_ + hu] = valid ? hn : 0.f;
}

// ---------------------------------------------------------------------------
// keys = memory[1024,1024] @ Wm[1024,1024]. Grid 256 = (64 rowtile, 4 cc).
// ---------------------------------------------------------------------------
__global__ __launch_bounds__(256) void keys_gemm_kernel(
    const float* __restrict__ memory, const float* __restrict__ Wm,
    float* __restrict__ keys)
{
    const int rt = blockIdx.x >> 2;
    const int cc = blockIdx.x & 3;
    const int col = cc * 256 + threadIdx.x;
    float acc[16];
    #pragma unroll
    for (int m = 0; m < 16; ++m) acc[m] = 0.f;
    for (int k = 0; k < H_; ++k) {
        const float w = Wm[(size_t)k * H_ + col];
        const float* mp = memory + (size_t)(rt * 16) * H_ + k;
        #pragma unroll
        for (int m = 0; m < 16; ++m)
            acc[m] = fmaf(mp[(size_t)m * H_], w, acc[m]);
    }
    #pragma unroll
    for (int m = 0; m < 16; ++m)
        keys[(size_t)(rt * 16 + m) * H_ + col] = acc[m];
}

// ---------------------------------------------------------------------------
// Decoder LSTM GEMM (split-K partials). x = [emb | attn | h], K=2304.
// Grid 512 = (16 colchunk, 32 ksplit).
// ---------------------------------------------------------------------------
__global__ __launch_bounds__(256) void dec_gemm_kernel(
    const float* __restrict__ emb, const int* __restrict__ dec_in,
    const float* __restrict__ Wk, const float* __restrict__ attn,
    const float* __restrict__ h_in, float* __restrict__ zpart, int t)
{
    const int cc = blockIdx.x & 15;
    const int ks = blockIdx.x >> 4;           // 0..31
    const int col = cc * 256 + threadIdx.x;
    const int k0 = ks * KSD_;

    int vidx[16];
    #pragma unroll
    for (int b = 0; b < 16; ++b) vidx[b] = dec_in[b * T_ + t];

    float acc[16];
    #pragma unroll
    for (int b = 0; b < 16; ++b) acc[b] = 0.f;

    for (int kk = 0; kk < KSD_; ++kk) {
        const int k = k0 + kk;
        const float w = Wk[(size_t)k * G4_ + col];
        if (k < E_) {
            #pragma unroll
            for (int b = 0; b < 16; ++b)
                acc[b] = fmaf(emb[(size_t)vidx[b] * E_ + k], w, acc[b]);
        } else if (k < E_ + H_) {
            const float* ap = attn + (k - E_);
            #pragma unroll
            for (int b = 0; b < 16; ++b)
                acc[b] = fmaf(ap[b * H_], w, acc[b]);
        } else {
            const float* hp = h_in + (k - E_ - H_);
            #pragma unroll
            for (int b = 0; b < 16; ++b)
                acc[b] = fmaf(hp[b * H_], w, acc[b]);
        }
    }
    #pragma unroll
    for (int b = 0; b < 16; ++b)
        zpart[((size_t)(ks * 16 + b)) * G4_ + col] = acc[b];
}

// ---------------------------------------------------------------------------
// Decoder gates (no masking on carry). Grid 64 x 256.
// ---------------------------------------------------------------------------
__global__ __launch_bounds__(256) void dec_gates_kernel(
    const float* __restrict__ zpart, const float* __restrict__ bias,
    float* __restrict__ h_out, float* __restrict__ c)
{
    const int idx = blockIdx.x * 256 + threadIdx.x;
    const int b = idx >> 10, hu = idx & 1023;
    float z[4];
    #pragma unroll
    for (int g = 0; g < 4; ++g) {
        float s0 = bias[g * H_ + hu], s1 = 0.f, s2 = 0.f, s3 = 0.f;
        #pragma unroll
        for (int ks = 0; ks < NKS_; ks += 4) {
            s0 += zpart[((size_t)((ks + 0) * 16 + b)) * G4_ + g * H_ + hu];
            s1 += zpart[((size_t)((ks + 1) * 16 + b)) * G4_ + g * H_ + hu];
            s2 += zpart[((size_t)((ks + 2) * 16 + b)) * G4_ + g * H_ + hu];
            s3 += zpart[((size_t)((ks + 3) * 16 + b)) * G4_ + g * H_ + hu];
        }
        z[g] = (s0 + s1) + (s2 + s3);
    }
    const float cold = c[b * H_ + hu];
    const float cn = cold * sigf(z[2] + 1.f) + sigf(z[0]) * tanhf(z[1]);
    const float hn = tanhf(cn) * sigf(z[3]);
    h_out[b * H_ + hu] = hn;
    c[b * H_ + hu] = cn;
}

// ---------------------------------------------------------------------------
// query partials: q = h2 @ Wq, split-K 32. Grid 128 = (4 cc, 32 ks).
// qpart layout: [ks][b][1024]
// ---------------------------------------------------------------------------
__global__ __launch_bounds__(256) void query_gemm_kernel(
    const float* __restrict__ h2, const float* __restrict__ Wq,
    float* __restrict__ qpart)
{
    const int cc = blockIdx.x & 3;
    const int ks = blockIdx.x >> 2;     // 0..31
    const int col = cc * 256 + threadIdx.x;
    const int k0 = ks * 32;
    float acc[16];
    #pragma unroll
    for (int b = 0; b < 16; ++b) acc[b] = 0.f;
    for (int kk = 0; kk < 32; ++kk) {
        const int k = k0 + kk;
        const float w = Wq[(size_t)k * H_ + col];
        const float* hp = h2 + k;
        #pragma unroll
        for (int b = 0; b < 16; ++b)
            acc[b] = fmaf(hp[b * H_], w, acc[b]);
    }
    #pragma unroll
    for (int b = 0; b < 16; ++b)
        qpart[((size_t)(ks * 16 + b)) * H_ + col] = acc[b];
}

// ---------------------------------------------------------------------------
// query finish: q[16][1024] = sum of 32 partials. Grid 64 x 256.
// ---------------------------------------------------------------------------
__global__ __launch_bounds__(256) void query_finish_kernel(
    const float* __restrict__ qpart, float* __restrict__ q)
{
    const int idx = blockIdx.x * 256 + threadIdx.x;
    const int b = idx >> 10, col = idx & 1023;
    float s0 = 0.f, s1 = 0.f, s2 = 0.f, s3 = 0.f;
    #pragma unroll
    for (int ks = 0; ks < 32; ks += 4) {
        s0 += qpart[((size_t)((ks + 0) * 16 + b)) * H_ + col];
        s1 += qpart[((size_t)((ks + 1) * 16 + b)) * H_ + col];
        s2 += qpart[((size_t)((ks + 2) * 16 + b)) * H_ + col];
        s3 += qpart[((size_t)((ks + 3) * 16 + b)) * H_ + col];
    }
    q[idx] = (s0 + s1) + (s2 + s3);
}

// ---------------------------------------------------------------------------
// scores[b][t] = sum_h tanh(keys[b,t,h] + q[b,h]) * v[h].
// Grid 1024 = (16 b, 64 t), 256 threads (4 h each).
// ---------------------------------------------------------------------------
__global__ __launch_bounds__(256) void attn_scores_kernel(
    const float* __restrict__ q, const float* __restrict__ keys,
    const float* __restrict__ v_att, float* __restrict__ scores)
{
    const int b = blockIdx.x >> 6, t = blockIdx.x & 63;
    const int tid = threadIdx.x;
    const float* kp = keys + ((size_t)b * T_ + t) * H_;
    const float* qp = q + b * H_;
    float s = 0.f;
    #pragma unroll
    for (int i = 0; i < 4; ++i) {
        const int h = tid + i * 256;
        s += tanhf(kp[h] + qp[h]) * v_att[h];
    }
    #pragma unroll
    for (int off = 32; off; off >>= 1) s += __shfl_xor(s, off);
    __shared__ float red[4];
    if ((tid & 63) == 0) red[tid >> 6] = s;
    __syncthreads();
    if (tid == 0) scores[b * T_ + t] = (red[0] + red[1]) + (red[2] + red[3]);
}

// ---------------------------------------------------------------------------
// masked softmax + context. Grid 64 = (16 b, 4 colchunk), 256 threads.
// 4 independent t-accumulators for ILP.
// ---------------------------------------------------------------------------
__global__ __launch_bounds__(256) void softmax_ctx_kernel(
    const float* __restrict__ scores, const float* __restrict__ memory,
    const int* __restrict__ enc_len, float* __restrict__ ctx)
{
    const int b = blockIdx.x >> 2, cc = blockIdx.x & 3;
    const int tid = threadIdx.x;
    __shared__ float al[T_];
    if (tid < 64) {
        const int len = enc_len[b];
        float s = (tid < len) ? scores[b * T_ + tid] : -1e9f;
        float m = s;
        #pragma unroll
        for (int off = 32; off; off >>= 1) m = fmaxf(m, __shfl_xor(m, off));
        float e = expf(s - m);
        float sum = e;
        #pragma unroll
        for (int off = 32; off; off >>= 1) sum += __shfl_xor(sum, off);
        al[tid] = e / sum;
    }
    __syncthreads();
    const int col = cc * 256 + tid;
    const float* mp = memory + (size_t)b * T_ * H_ + col;
    float a0 = 0.f, a1 = 0.f, a2 = 0.f, a3 = 0.f;
    #pragma unroll
    for (int t2 = 0; t2 < T_; t2 += 4) {
        a0 = fmaf(al[t2 + 0], mp[(size_t)(t2 + 0) * H_], a0);
        a1 = fmaf(al[t2 + 1], mp[(size_t)(t2 + 1) * H_], a1);
        a2 = fmaf(al[t2 + 2], mp[(size_t)(t2 + 2) * H_], a2);
        a3 = fmaf(al[t2 + 3], mp[(size_t)(t2 + 3) * H_], a3);
    }
    ctx[b * H_ + col] = (a0 + a1) + (a2 + a3);
}

// ---------------------------------------------------------------------------
// attn2 partials: [h2|ctx](K=2048) @ attn_kernel, split-K 32.
// Grid 128 = (4 cc, 32 ks). apart layout: [ks][b][1024]
// ---------------------------------------------------------------------------
__global__ __launch_bounds__(256) void attnout_gemm_kernel(
    const float* __restrict__ h2, const float* __restrict__ ctx,
    const float* __restrict__ attn_k, float* __restrict__ apart)
{
    const int cc = blockIdx.x & 3;
    const int ks = blockIdx.x >> 2;     // 0..31
    const int col = cc * 256 + threadIdx.x;
    const int k0 = ks * 64;
    float acc[16];
    #pragma unroll
    for (int b = 0; b < 16; ++b) acc[b] = 0.f;
    for (int kk = 0; kk < 64; ++kk) {
        const int k = k0 + kk;
        const float w = attn_k[(size_t)k * H_ + col];
        const float* xp = (k < H_) ? (h2 + k) : (ctx + (k - H_));
        #pragma unroll
        for (int b = 0; b < 16; ++b)
            acc[b] = fmaf(xp[b * H_], w, acc[b]);
    }
    #pragma unroll
    for (int b = 0; b < 16; ++b)
        apart[((size_t)(ks * 16 + b)) * H_ + col] = acc[b];
}

// ---------------------------------------------------------------------------
// attn_out finish: reduce 32 partials -> attn state (carry, unmasked) and
// dec_out (fp32, zeroed where finished). Grid 64 x 256.
// ---------------------------------------------------------------------------
__global__ __launch_bounds__(256) void attnout_finish_kernel(
    const float* __restrict__ apart, const int* __restrict__ dec_len,
    float* __restrict__ attn_state, float* __restrict__ dec_out, int t)
{
    const int idx = blockIdx.x * 256 + threadIdx.x;
    const int b = idx >> 10, col = idx & 1023;
    float s0 = 0.f, s1 = 0.f, s2 = 0.f, s3 = 0.f;
    #pragma unroll
    for (int ks = 0; ks < 32; ks += 4) {
        s0 += apart[((size_t)((ks + 0) * 16 + b)) * H_ + col];
        s1 += apart[((size_t)((ks + 1) * 16 + b)) * H_ + col];
        s2 += apart[((size_t)((ks + 2) * 16 + b)) * H_ + col];
        s3 += apart[((size_t)((ks + 3) * 16 + b)) * H_ + col];
    }
    const float s = (s0 + s1) + (s2 + s3);
    attn_state[b * H_ + col] = s;
    const bool fin = t >= dec_len[b];
    dec_out[((size_t)b * T_ + t) * H_ + col] = fin ? 0.f : s;
}

// ---------------------------------------------------------------------------
// logits = dec_out(fp32 [1024,1024]) @ out_kernel(fp32 [1024,32000]) -> fp32.
// Split-bf16: D = ah*bh + ah*bl + al*bh. MFMA 16x16x32_bf16, 64x64 tile.
// ---------------------------------------------------------------------------
typedef __attribute__((ext_vector_type(8))) short short8;
typedef __attribute__((ext_vector_type(4))) float float4v;

__global__ __launch_bounds__(256) void logits_kernel(
    const float* __restrict__ A, const float* __restrict__ Bw,
    float* __restrict__ out)
{
    __shared__ __align__(16) ushort_t Ah[64][40];
    __shared__ __align__(16) ushort_t Al[64][40];
    __shared__ __align__(16) ushort_t Bh[64][40];   // transposed: [n][k]
    __shared__ __align__(16) ushort_t Bl[64][40];
    const int tid = threadIdx.x;
    const int m0 = blockIdx.x * 64;
    const int n0 = blockIdx.y * 64;
    const int wv = tid >> 6, lane = tid & 63;
    const int ml = lane & 15, quad = lane >> 4;

    float4v acc[4];
    #pragma unroll
    for (int nn = 0; nn < 4; ++nn) acc[nn] = (float4v){0.f, 0.f, 0.f, 0.f};

    for (int kb = 0; kb < 1024; kb += 32) {
        __syncthreads();
        {   // stage A: 64 rows x 32 k fp32 -> hi/lo bf16
            const int r = tid >> 2, c0 = (tid & 3) * 8;
            const float* ap = A + (size_t)(m0 + r) * 1024 + kb + c0;
            #pragma unroll
            for (int i = 0; i < 8; ++i) {
                const float f = ap[i];
                const ushort_t hi = f2b(f);
                Ah[r][c0 + i] = hi;
                Al[r][c0 + i] = f2b(f - b2f(hi));
            }
        }
        {   // stage B transposed: coalesced rows, fp32 -> hi/lo bf16
            const int cB = tid & 63, kq = tid >> 6;
            #pragma unroll
            for (int i = 0; i < 8; ++i) {
                const int k = kq * 8 + i;
                const float f = Bw[(size_t)(kb + k) * V_ + n0 + cB];
                const ushort_t hi = f2b(f);
                Bh[cB][k] = hi;
                Bl[cB][k] = f2b(f - b2f(hi));
            }
        }
        __syncthreads();
        const short8 afh = *(const short8*)&Ah[wv * 16 + ml][quad * 8];
        const short8 afl = *(const short8*)&Al[wv * 16 + ml][quad * 8];
        #pragma unroll
        for (int nn = 0; nn < 4; ++nn) {
            const short8 bfh = *(const short8*)&Bh[nn * 16 + ml][quad * 8];
            const short8 bfl = *(const short8*)&Bl[nn * 16 + ml][quad * 8];
            acc[nn] = __builtin_amdgcn_mfma_f32_16x16x32_bf16(afh, bfh, acc[nn], 0, 0, 0);
            acc[nn] = __builtin_amdgcn_mfma_f32_16x16x32_bf16(afh, bfl, acc[nn], 0, 0, 0);
            acc[nn] = __builtin_amdgcn_mfma_f32_16x16x32_bf16(afl, bfh, acc[nn], 0, 0, 0);
        }
    }
    #pragma unroll
    for (int nn = 0; nn < 4; ++nn) {
        #pragma unroll
        for (int rg = 0; rg < 4; ++rg) {
            const int row = m0 + wv * 16 + quad * 4 + rg;
            const int colo = n0 + nn * 16 + ml;
            out[(size_t)row * V_ + colo] = acc[nn][rg];
        }
    }
}

// ---------------------------------------------------------------------------
extern "C" void kernel_launch(void* const* d_in, const int* in_sizes, int n_in,
                              void* d_out, int out_size, void* d_ws, size_t ws_size,
                              hipStream_t stream) {
    (void)in_sizes; (void)n_in; (void)out_size; (void)ws_size;
    const int*   enc_in  = (const int*)d_in[0];
    const int*   dec_in  = (const int*)d_in[1];
    const int*   enc_len = (const int*)d_in[2];
    const int*   dec_len = (const int*)d_in[3];
    const float* emb     = (const float*)d_in[4];
    const float* encK    = (const float*)d_in[5];
    const float* encB    = (const float*)d_in[6];
    const float* decK    = (const float*)d_in[7];
    const float* decB    = (const float*)d_in[8];
    const float* Wm      = (const float*)d_in[9];
    const float* Wq      = (const float*)d_in[10];
    const float* v_att   = (const float*)d_in[11];
    const float* attnK   = (const float*)d_in[12];
    const float* outK    = (const float*)d_in[13];
    float* out = (float*)d_out;

    // fp32 workspace layout (~21.4 MB). qpart/apart alias zpart (phases are
    // sequential within a step: zpart dead after gates; qpart dead after
    // query_finish; apart at +2MB offset).
    float* hbuf    = (float*)d_ws;                      // 2 x [16,1024]
    float* cbuf    = hbuf + 2 * B_ * H_;                // [16,1024]
    float* attn    = cbuf + B_ * H_;                    // [16,1024]
    float* ctx     = attn + B_ * H_;                    // [16,1024]
    float* q       = ctx + B_ * H_;                     // [16,1024]
    float* scores  = q + B_ * H_;                       // [16,64]
    float* memory  = scores + B_ * T_;                  // [16,64,1024]
    float* keys    = memory + (size_t)B_ * T_ * H_;     // [16,64,1024]
    float* dec_out = keys + (size_t)B_ * T_ * H_;       // [1024,1024]
    float* zpart   = dec_out + (size_t)B_ * T_ * H_;    // [32][16][4096] = 8MB
    float* qpart   = zpart;                             // [32][16][1024] alias
    float* apart   = zpart + (size_t)32 * B_ * H_;      // [32][16][1024] alias

    // zero fp32 recurrent state (ws poisoned 0xAA): hbuf x2, c, attn
    const int ninit = 4 * B_ * H_;
    init_kernel<<<(ninit + 255) / 256, 256, 0, stream>>>((float*)d_ws, ninit);

    for (int t = 0; t < T_; ++t) {
        float* h_in  = hbuf + (t & 1) * B_ * H_;
        float* h_out = hbuf + ((t + 1) & 1) * B_ * H_;
        enc_gemm_kernel<<<512, 256, 0, stream>>>(emb, enc_in, encK, h_in, zpart, t);
        enc_gates_kernel<<<64, 256, 0, stream>>>(zpart, encB, enc_len, h_in,
                                                 h_out, cbuf, memory, t);
    }
    keys_gemm_kernel<<<256, 256, 0, stream>>>(memory, Wm, keys);

    for (int t = 0; t < T_; ++t) {
        float* h_in  = hbuf + (t & 1) * B_ * H_;
        float* h2    = hbuf + ((t + 1) & 1) * B_ * H_;
        dec_gemm_kernel<<<512, 256, 0, stream>>>(emb, dec_in, decK, attn, h_in, zpart, t);
        dec_gates_kernel<<<64, 256, 0, stream>>>(zpart, decB, h2, cbuf);
        query_gemm_kernel<<<128, 256, 0, stream>>>(h2, Wq, qpart);
        query_finish_kernel<<<64, 256, 0, stream>>>(qpart, q);
        attn_scores_kernel<<<1024, 256, 0, stream>>>(q, keys, v_att, scores);
        softmax_ctx_kernel<<<64, 256, 0, stream>>>(scores, memory, enc_len, ctx);
        attnout_gemm_kernel<<<128, 256, 0, stream>>>(h2, ctx, attnK, apart);
        attnout_finish_kernel<<<64, 256, 0, stream>>>(apart, dec_len, attn, dec_out, t);
    }

    logits_kernel<<<dim3(16, 500), 256, 0, stream>>>(dec_out, outK, out);
}